// Round 7
// baseline (101.037 us; speedup 1.0000x reference)
//
#include <hip/hip_runtime.h>
#include <hip/hip_bf16.h>

#define N_ 256
#define S_ 128
#define H_ 512
#define E_ 256
#define O_ 32000
#define KZ 1792   // z row: 1024 ctx + 256 emb + 512 h
#define GJ 2048
#define KSPLIT 4
#define KCHUNK 448  // 14 steps of 32
#define SSPLIT 4

typedef __attribute__((ext_vector_type(8))) short sv8;
typedef __attribute__((ext_vector_type(4))) float fv4;

__device__ __forceinline__ unsigned short f2bf(float f) {
  return __builtin_bit_cast(unsigned short, __float2bfloat16(f));
}

__device__ __forceinline__ sv8 pack8(fv4 a, fv4 b) {
  sv8 r;
  r[0] = (short)f2bf(a[0]); r[1] = (short)f2bf(a[1]);
  r[2] = (short)f2bf(a[2]); r[3] = (short)f2bf(a[3]);
  r[4] = (short)f2bf(b[0]); r[5] = (short)f2bf(b[1]);
  r[6] = (short)f2bf(b[2]); r[7] = (short)f2bf(b[3]);
  return r;
}

// ---------------- K1a: partial attention over an S-quarter  (+ merged W-gate conv plane)
// grid (256, SSPLIT+1): y<SSPLIT = attention quarters; y==SSPLIT = [Wih|Whh]->bf16 stream
__global__ __launch_bounds__(512) void k_attn_part(
    const float* __restrict__ eo, const float* __restrict__ hid,
    const float* __restrict__ We, const float* __restrict__ be,
    const float* __restrict__ Wih, const float* __restrict__ Whh,
    unsigned short* __restrict__ Wgbf,
    float* __restrict__ pctx, float* __restrict__ pml)
{
  if (blockIdx.y == SSPLIT) {
    // streaming conversion: 2048 rows x 224 sv8-chunks (160 Wih + 64 Whh)
    const int tid = blockIdx.x * 512 + threadIdx.x;   // 131072 threads
    for (int g = tid; g < 2048 * 224; g += 256 * 512) {
      const int j = g / 224, c = g - j * 224;
      sv8* dst = (sv8*)(Wgbf + (size_t)j * KZ);
      if (c < 160) {
        const fv4* src = (const fv4*)(Wih + (size_t)j * 1280);
        dst[c] = pack8(src[2 * c], src[2 * c + 1]);
      } else {
        const int cc = c - 160;
        const fv4* src = (const fv4*)(Whh + (size_t)j * 512);
        dst[c] = pack8(src[2 * cc], src[2 * cc + 1]);
      }
    }
    return;
  }

  const int n = blockIdx.x;
  const int q = blockIdx.y;
  const int t = threadIdx.x;
  const int w = t >> 6;
  const int l = t & 63;

  __shared__ float s_red[8];
  __shared__ float s_m[8], s_l[8];
  __shared__ float s_ctx[8][1024];

  float hv = hid[(size_t)n * H_ + t] * We[t];
  #pragma unroll
  for (int off = 32; off >= 1; off >>= 1) hv += __shfl_xor(hv, off);
  if (l == 0) s_red[w] = hv;
  __syncthreads();
  float hWe = be[0];
  #pragma unroll
  for (int i = 0; i < 8; ++i) hWe += s_red[i];

  fv4 we0, we1, we2, we3;
  {
    const fv4* wp = (const fv4*)(We + H_);
    we0 = wp[l]; we1 = wp[l + 64]; we2 = wp[l + 128]; we3 = wp[l + 192];
  }

  float m = 0.f, lsum = 0.f;
  fv4 c0 = {0,0,0,0}, c1 = {0,0,0,0}, c2 = {0,0,0,0}, c3 = {0,0,0,0};
  const float* eob = eo + ((size_t)n * S_ + q * 32 + w * 4) * 1024;
  #pragma unroll 2
  for (int i = 0; i < 4; ++i) {
    const fv4* p = (const fv4*)(eob + (size_t)i * 1024);
    fv4 v0 = p[l], v1 = p[l + 64], v2 = p[l + 128], v3 = p[l + 192];
    float d = 0.f;
    #pragma unroll
    for (int c = 0; c < 4; ++c)
      d += v0[c]*we0[c] + v1[c]*we1[c] + v2[c]*we2[c] + v3[c]*we3[c];
    #pragma unroll
    for (int off = 32; off >= 1; off >>= 1) d += __shfl_xor(d, off);
    const float e  = fmaxf(d + hWe, 0.f);
    const float mn = fmaxf(m, e);
    const float sc = __expf(m - mn);
    const float pp = __expf(e - mn);
    lsum = lsum * sc + pp;
    #pragma unroll
    for (int c = 0; c < 4; ++c) {
      c0[c] = c0[c]*sc + pp*v0[c];
      c1[c] = c1[c]*sc + pp*v1[c];
      c2[c] = c2[c]*sc + pp*v2[c];
      c3[c] = c3[c]*sc + pp*v3[c];
    }
    m = mn;
  }
  if (l == 0) { s_m[w] = m; s_l[w] = lsum; }
  {
    fv4* sc_ = (fv4*)s_ctx[w];
    sc_[l] = c0; sc_[l+64] = c1; sc_[l+128] = c2; sc_[l+192] = c3;
  }
  __syncthreads();

  float M = s_m[0];
  #pragma unroll
  for (int i = 1; i < 8; ++i) M = fmaxf(M, s_m[i]);
  float wgt[8]; float L = 0.f;
  #pragma unroll
  for (int i = 0; i < 8; ++i) { wgt[i] = __expf(s_m[i] - M); L += wgt[i] * s_l[i]; }

  float* pc = pctx + ((size_t)(n * SSPLIT + q)) * 1024;
  for (int k = t; k < 1024; k += 512) {
    float acc = 0.f;
    #pragma unroll
    for (int i = 0; i < 8; ++i) acc += wgt[i] * s_ctx[i][k];
    pc[k] = acc;
  }
  if (t == 0) {
    pml[(n * SSPLIT + q) * 2 + 0] = M;
    pml[(n * SSPLIT + q) * 2 + 1] = L;
  }
}

// ---------------- K1b: combine quarters -> z (bf16 [256][1792]) + emb + h copy
__global__ __launch_bounds__(256) void k_attn_fin(
    const int* __restrict__ x, const float* __restrict__ emb,
    const float* __restrict__ hid, const float* __restrict__ pctx,
    const float* __restrict__ pml, unsigned short* __restrict__ z)
{
  const int n = blockIdx.x;
  const int t = threadIdx.x;
  float mq[SSPLIT], lq[SSPLIT];
  #pragma unroll
  for (int q = 0; q < SSPLIT; ++q) {
    mq[q] = pml[(n * SSPLIT + q) * 2 + 0];
    lq[q] = pml[(n * SSPLIT + q) * 2 + 1];
  }
  float M = mq[0];
  #pragma unroll
  for (int q = 1; q < SSPLIT; ++q) M = fmaxf(M, mq[q]);
  float wq[SSPLIT], L = 0.f;
  #pragma unroll
  for (int q = 0; q < SSPLIT; ++q) { wq[q] = __expf(mq[q] - M); L += wq[q] * lq[q]; }
  const float rL = 1.f / L;

  const fv4* p0 = (const fv4*)(pctx + (size_t)n * (SSPLIT * 1024));
  fv4 s = {0,0,0,0};
  #pragma unroll
  for (int q = 0; q < SSPLIT; ++q) {
    const fv4 v = p0[q * 256 + t];
    #pragma unroll
    for (int c = 0; c < 4; ++c) s[c] += wq[q] * v[c];
  }
  unsigned short* zr = z + (size_t)n * KZ;
  ushort4 o;
  o.x = f2bf(s[0] * rL);
  o.y = f2bf(s[1] * rL);
  o.z = f2bf(s[2] * rL);
  o.w = f2bf(s[3] * rL);
  *(ushort4*)(zr + 4*t) = o;

  zr[1024 + t] = f2bf(emb[(size_t)x[n] * E_ + t]);
  zr[1280 + t] = f2bf(hid[(size_t)n * H_ + t]);
  zr[1536 + t] = f2bf(hid[(size_t)n * H_ + 256 + t]);
}

// ---------------- K2: partial gates = z @ Wg^T  (bf16 MFMA, K-split, n-tile 32)
// grid (32 j-tiles, 8 n-tiles, 4 k-chunks) = 1024 blocks
__global__ __launch_bounds__(256) void k_gates(
    const unsigned short* __restrict__ z, const unsigned short* __restrict__ Wgbf,
    float* __restrict__ part)
{
  const int j0 = blockIdx.x * 64;
  const int n0 = blockIdx.y * 32;
  const int kc = blockIdx.z * KCHUNK;
  const int t = threadIdx.x;
  const int w = t >> 6, l = t & 63;
  const int lr = l & 15, lg = l >> 4;
  const int jb = j0 + w * 16 + lr;

  const unsigned short* arow = z + kc + 8 * lg;
  const unsigned short* wrow = Wgbf + (size_t)jb * KZ + kc + 8 * lg;

  fv4 acc[2] = {{0,0,0,0},{0,0,0,0}};
  #pragma unroll
  for (int s = 0; s < 14; ++s) {
    const sv8 bf = *(const sv8*)(wrow + s * 32);
    #pragma unroll
    for (int f = 0; f < 2; ++f) {
      const sv8 af = *(const sv8*)(arow + (size_t)(n0 + f*16 + lr) * KZ + s * 32);
      acc[f] = __builtin_amdgcn_mfma_f32_16x16x32_bf16(af, bf, acc[f], 0, 0, 0);
    }
  }
  float* pp = part + (size_t)blockIdx.z * (N_ * GJ);
  #pragma unroll
  for (int f = 0; f < 2; ++f) {
    #pragma unroll
    for (int r = 0; r < 4; ++r)
      pp[(size_t)(n0 + f*16 + lg*4 + r) * GJ + jb] = acc[f][r];
  }
}

// ---------------- K3: LSTM cell elementwise; reduces K-split partials + biases
__global__ __launch_bounds__(256) void k_lstm(
    const float* __restrict__ part, const float* __restrict__ cell,
    const float* __restrict__ bih, const float* __restrict__ bhh,
    float* __restrict__ hout, float* __restrict__ cout,
    unsigned short* __restrict__ hbf)
{
  const int tid = blockIdx.x * 256 + threadIdx.x;
  const int n = tid >> 9, hh = tid & 511;
  const size_t base = (size_t)n * GJ;
  float ig = bih[hh]        + bhh[hh];
  float fg = bih[512 + hh]  + bhh[512 + hh];
  float gg = bih[1024 + hh] + bhh[1024 + hh];
  float og = bih[1536 + hh] + bhh[1536 + hh];
  #pragma unroll
  for (int k = 0; k < KSPLIT; ++k) {
    const float* p = part + (size_t)k * (N_ * GJ) + base;
    ig += p[hh];
    fg += p[512 + hh];
    gg += p[1024 + hh];
    og += p[1536 + hh];
  }
  ig = 1.f / (1.f + __expf(-ig));
  fg = 1.f / (1.f + __expf(-fg));
  og = 1.f / (1.f + __expf(-og));
  gg = tanhf(gg);
  const float c = fg * cell[tid] + ig * gg;
  const float h = og * tanhf(c);
  cout[tid] = c;
  hout[tid] = h;
  hbf[tid] = f2bf(h);
}

// ---------------- K4: predictions = h_new @ W_out^T + b_out
// 32 o-cols x 256 n-rows per block; 256 thr / 4 waves (wave = 64 n x 32 o);
// W_out f32 staged+converted into 32 KB XOR-swizzled LDS; 4 blocks/CU.
__global__ __launch_bounds__(256, 4) void k_pred(
    const unsigned short* __restrict__ hbf, const float* __restrict__ Wout,
    const float* __restrict__ bout, float* __restrict__ pred)
{
  __shared__ unsigned short Blds[32 * 512];   // 32 KB, row = o-col, 1024 B/row
  const int o0 = blockIdx.x * 32;
  const int t = threadIdx.x;

  // stage+convert: 2048 16B-chunks, 8 per thread
  #pragma unroll
  for (int i = 0; i < 8; ++i) {
    const int g = t + i * 256;
    const int row = g >> 6, c = g & 63;
    const fv4* src = (const fv4*)(Wout + (size_t)(o0 + row) * H_ + c * 8);
    const sv8 v = pack8(src[0], src[1]);
    *(sv8*)((char*)Blds + row * 1024 + ((c * 16) ^ ((row & 7) << 4))) = v;
  }
  __syncthreads();

  const int w = t >> 6, l = t & 63;
  const int lr = l & 15, lg = l >> 4;
  const int nr = w * 64;   // wave handles 64 n-rows x 32 o-cols

  fv4 acc[4][2] = {};
  #pragma unroll
  for (int kk = 0; kk < 16; ++kk) {
    sv8 a[4];
    #pragma unroll
    for (int f = 0; f < 4; ++f)
      a[f] = *(const sv8*)(hbf + (size_t)(nr + f*16 + lr) * H_ + kk*32 + 8*lg);
    #pragma unroll
    for (int fo = 0; fo < 2; ++fo) {
      const int row = fo * 16 + lr;
      const sv8 b = *(const sv8*)((const char*)Blds + row * 1024 +
                                  ((kk*64 + lg*16) ^ ((row & 7) << 4)));
      #pragma unroll
      for (int f = 0; f < 4; ++f)
        acc[f][fo] = __builtin_amdgcn_mfma_f32_16x16x32_bf16(a[f], b, acc[f][fo], 0, 0, 0);
    }
  }
  #pragma unroll
  for (int fo = 0; fo < 2; ++fo) {
    const int oo = o0 + fo*16 + lr;
    const float bo = bout[oo];
    #pragma unroll
    for (int f = 0; f < 4; ++f) {
      #pragma unroll
      for (int r = 0; r < 4; ++r)
        pred[(size_t)(nr + f*16 + lg*4 + r) * O_ + oo] = acc[f][fo][r] + bo;
    }
  }
}

extern "C" void kernel_launch(void* const* d_in, const int* in_sizes, int n_in,
                              void* d_out, int out_size, void* d_ws, size_t ws_size,
                              hipStream_t stream) {
  const int*   x    = (const int*)  d_in[0];
  const float* eo   = (const float*)d_in[1];
  const float* hid  = (const float*)d_in[2];
  const float* cell = (const float*)d_in[3];
  const float* emb  = (const float*)d_in[4];
  const float* We   = (const float*)d_in[5];
  const float* be   = (const float*)d_in[6];
  const float* Wih  = (const float*)d_in[7];
  const float* Whh  = (const float*)d_in[8];
  const float* bih  = (const float*)d_in[9];
  const float* bhh  = (const float*)d_in[10];
  const float* Wout = (const float*)d_in[11];
  const float* bout = (const float*)d_in[12];

  float* pred = (float*)d_out;
  float* hout = pred + (size_t)N_ * O_;
  float* cout = hout + (size_t)N_ * H_;

  unsigned short* z    = (unsigned short*)d_ws;           // 917504 B
  unsigned short* hbf  = z + (size_t)N_ * KZ;             // 262144 B
  float* part = (float*)(hbf + (size_t)N_ * H_);          // 8 MB
  float* pctx = part + (size_t)KSPLIT * N_ * GJ;          // 4 MB
  float* pml  = pctx + (size_t)N_ * SSPLIT * 1024;        // 8 KB
  unsigned short* Wgbf = (unsigned short*)(pml + 2048);   // 7.34 MB

  k_attn_part<<<dim3(256, SSPLIT + 1), 512, 0, stream>>>(eo, hid, We, be,
                                                         Wih, Whh, Wgbf, pctx, pml);
  k_attn_fin <<<256, 256, 0, stream>>>(x, emb, hid, pctx, pml, z);
  k_gates<<<dim3(32, 8, KSPLIT), 256, 0, stream>>>(z, Wgbf, part);
  k_lstm <<<512, 256, 0, stream>>>(part, cell, bih, bhh, hout, cout, hbf);
  k_pred <<<1000, 256, 0, stream>>>(hbf, Wout, bout, pred);
}

// Round 8
// 88.708 us; speedup vs baseline: 1.1390x; 1.1390x over previous
//
#include <hip/hip_runtime.h>
#include <hip/hip_bf16.h>

#define N_ 256
#define S_ 128
#define H_ 512
#define E_ 256
#define O_ 32000
#define KZ 1792   // z row: 1024 ctx + 256 emb + 512 h
#define GJ 2048
#define KSPLIT 4
#define KCHUNK 448  // 14 steps of 32

typedef __attribute__((ext_vector_type(8))) short sv8;
typedef __attribute__((ext_vector_type(4))) float fv4;

__device__ __forceinline__ unsigned short f2bf(float f) {
  return __builtin_bit_cast(unsigned short, __float2bfloat16(f));
}

__device__ __forceinline__ sv8 pack8(fv4 a, fv4 b) {
  sv8 r;
  r[0] = (short)f2bf(a[0]); r[1] = (short)f2bf(a[1]);
  r[2] = (short)f2bf(a[2]); r[3] = (short)f2bf(a[3]);
  r[4] = (short)f2bf(b[0]); r[5] = (short)f2bf(b[1]);
  r[6] = (short)f2bf(b[2]); r[7] = (short)f2bf(b[3]);
  return r;
}

// ---------------- K1: full attention per n (16 waves x 8 s-rows, in-block combine)
// grid (256, 2): y==0 attention -> z directly; y==1 [Wih|Whh]->bf16 stream
__global__ __launch_bounds__(1024) void k_attn(
    const int* __restrict__ x, const float* __restrict__ eo,
    const float* __restrict__ hid, const float* __restrict__ emb,
    const float* __restrict__ We, const float* __restrict__ be,
    const float* __restrict__ Wih, const float* __restrict__ Whh,
    unsigned short* __restrict__ Wgbf, unsigned short* __restrict__ z)
{
  if (blockIdx.y == 1) {
    // streaming conversion: 2048 rows x 224 sv8-chunks (160 Wih + 64 Whh)
    const int tid = blockIdx.x * 1024 + threadIdx.x;   // 262144 threads
    for (int g = tid; g < 2048 * 224; g += 256 * 1024) {
      const int j = g / 224, c = g - j * 224;
      sv8* dst = (sv8*)(Wgbf + (size_t)j * KZ);
      if (c < 160) {
        const fv4* src = (const fv4*)(Wih + (size_t)j * 1280);
        dst[c] = pack8(src[2 * c], src[2 * c + 1]);
      } else {
        const int cc = c - 160;
        const fv4* src = (const fv4*)(Whh + (size_t)j * 512);
        dst[c] = pack8(src[2 * cc], src[2 * cc + 1]);
      }
    }
    return;
  }

  const int n = blockIdx.x;
  const int t = threadIdx.x;
  const int w = t >> 6;    // 0..15
  const int l = t & 63;

  __shared__ float s_red[16];
  __shared__ float s_m[16], s_l[16];
  __shared__ float s_ctx[16][1024];   // 64 KB

  // hWe = h[n] . We[0:512] + b_energy  (waves 0..7 hold t<512)
  float hv = (t < 512) ? hid[(size_t)n * H_ + t] * We[t] : 0.f;
  #pragma unroll
  for (int off = 32; off >= 1; off >>= 1) hv += __shfl_xor(hv, off);
  if (l == 0) s_red[w] = hv;
  __syncthreads();
  float hWe = be[0];
  #pragma unroll
  for (int i = 0; i < 8; ++i) hWe += s_red[i];

  // loop-invariant We_eo fragment: elems 4l + 256j
  fv4 we0, we1, we2, we3;
  {
    const fv4* wp = (const fv4*)(We + H_);
    we0 = wp[l]; we1 = wp[l + 64]; we2 = wp[l + 128]; we3 = wp[l + 192];
  }

  // online softmax over this wave's 8 s-rows; ctx in regs
  float m = 0.f, lsum = 0.f;
  fv4 c0 = {0,0,0,0}, c1 = {0,0,0,0}, c2 = {0,0,0,0}, c3 = {0,0,0,0};
  const float* eob = eo + ((size_t)n * S_ + w * 8) * 1024;
  #pragma unroll 2
  for (int i = 0; i < 8; ++i) {
    const fv4* p = (const fv4*)(eob + (size_t)i * 1024);
    fv4 v0 = p[l], v1 = p[l + 64], v2 = p[l + 128], v3 = p[l + 192];
    float d = 0.f;
    #pragma unroll
    for (int c = 0; c < 4; ++c)
      d += v0[c]*we0[c] + v1[c]*we1[c] + v2[c]*we2[c] + v3[c]*we3[c];
    #pragma unroll
    for (int off = 32; off >= 1; off >>= 1) d += __shfl_xor(d, off);
    const float e  = fmaxf(d + hWe, 0.f);
    const float mn = fmaxf(m, e);
    const float sc = __expf(m - mn);
    const float pp = __expf(e - mn);
    lsum = lsum * sc + pp;
    #pragma unroll
    for (int c = 0; c < 4; ++c) {
      c0[c] = c0[c]*sc + pp*v0[c];
      c1[c] = c1[c]*sc + pp*v1[c];
      c2[c] = c2[c]*sc + pp*v2[c];
      c3[c] = c3[c]*sc + pp*v3[c];
    }
    m = mn;
  }
  if (l == 0) { s_m[w] = m; s_l[w] = lsum; }
  {
    fv4* sc_ = (fv4*)s_ctx[w];
    sc_[l] = c0; sc_[l+64] = c1; sc_[l+128] = c2; sc_[l+192] = c3;
  }
  __syncthreads();

  // cross-wave softmax merge (exact)
  float M = s_m[0];
  #pragma unroll
  for (int i = 1; i < 16; ++i) M = fmaxf(M, s_m[i]);
  float wgt[16]; float L = 0.f;
  #pragma unroll
  for (int i = 0; i < 16; ++i) { wgt[i] = __expf(s_m[i] - M); L += wgt[i] * s_l[i]; }
  const float rL = 1.f / L;

  float acc = 0.f;
  #pragma unroll
  for (int i = 0; i < 16; ++i) acc += wgt[i] * s_ctx[i][t];
  unsigned short* zr = z + (size_t)n * KZ;
  zr[t] = f2bf(acc * rL);

  if (t < 256)       zr[1024 + t] = f2bf(emb[(size_t)x[n] * E_ + t]);
  else if (t < 768)  zr[1024 + t] = f2bf(hid[(size_t)n * H_ + (t - 256)]);
}

// ---------------- K2: partial gates = z @ Wg^T  (bf16 MFMA, K-split, branch-free)
// grid (32 j-tiles, 4 n-tiles, 4 k-chunks)
__global__ __launch_bounds__(256) void k_gates(
    const unsigned short* __restrict__ z, const unsigned short* __restrict__ Wgbf,
    float* __restrict__ part)
{
  const int j0 = blockIdx.x * 64;
  const int n0 = blockIdx.y * 64;
  const int kc = blockIdx.z * KCHUNK;
  const int t = threadIdx.x;
  const int w = t >> 6, l = t & 63;
  const int lr = l & 15, lg = l >> 4;
  const int jb = j0 + w * 16 + lr;

  const unsigned short* arow = z + kc + 8 * lg;
  const unsigned short* wrow = Wgbf + (size_t)jb * KZ + kc + 8 * lg;

  fv4 acc[4] = {{0,0,0,0},{0,0,0,0},{0,0,0,0},{0,0,0,0}};
  #pragma unroll
  for (int s = 0; s < 14; ++s) {
    const sv8 bf = *(const sv8*)(wrow + s * 32);
    #pragma unroll
    for (int f = 0; f < 4; ++f) {
      const sv8 af = *(const sv8*)(arow + (size_t)(n0 + f*16 + lr) * KZ + s * 32);
      acc[f] = __builtin_amdgcn_mfma_f32_16x16x32_bf16(af, bf, acc[f], 0, 0, 0);
    }
  }
  float* pp = part + (size_t)blockIdx.z * (N_ * GJ);
  #pragma unroll
  for (int f = 0; f < 4; ++f) {
    #pragma unroll
    for (int r = 0; r < 4; ++r)
      pp[(size_t)(n0 + f*16 + lg*4 + r) * GJ + jb] = acc[f][r];
  }
}

// ---------------- K3: LSTM cell elementwise; reduces K-split partials + biases
__global__ __launch_bounds__(256) void k_lstm(
    const float* __restrict__ part, const float* __restrict__ cell,
    const float* __restrict__ bih, const float* __restrict__ bhh,
    float* __restrict__ hout, float* __restrict__ cout,
    unsigned short* __restrict__ hbf)
{
  const int tid = blockIdx.x * 256 + threadIdx.x;
  const int n = tid >> 9, hh = tid & 511;
  const size_t base = (size_t)n * GJ;
  float ig = bih[hh]        + bhh[hh];
  float fg = bih[512 + hh]  + bhh[512 + hh];
  float gg = bih[1024 + hh] + bhh[1024 + hh];
  float og = bih[1536 + hh] + bhh[1536 + hh];
  #pragma unroll
  for (int k = 0; k < KSPLIT; ++k) {
    const float* p = part + (size_t)k * (N_ * GJ) + base;
    ig += p[hh];
    fg += p[512 + hh];
    gg += p[1024 + hh];
    og += p[1536 + hh];
  }
  ig = 1.f / (1.f + __expf(-ig));
  fg = 1.f / (1.f + __expf(-fg));
  og = 1.f / (1.f + __expf(-og));
  gg = tanhf(gg);
  const float c = fg * cell[tid] + ig * gg;
  const float h = og * tanhf(c);
  cout[tid] = c;
  hout[tid] = h;
  hbf[tid] = f2bf(h);
}

// ---------------- K4: predictions = h_new @ W_out^T + b_out
// LDS-staged: block = 64 o-cols x all 256 n-rows; W_out f32 -> bf16 packed into
// XOR-swizzled LDS once, then 16 unrolled K-steps of pure ds_read + MFMA.
__global__ __launch_bounds__(512, 2) void k_pred(
    const unsigned short* __restrict__ hbf, const float* __restrict__ Wout,
    const float* __restrict__ bout, float* __restrict__ pred)
{
  __shared__ unsigned short Blds[64 * 512];   // 64 KB, row = o-col, 1024 B/row
  const int o0 = blockIdx.x * 64;
  const int t = threadIdx.x;

  // stage+convert: 4096 16B-chunks, 8 per thread; chunk c of row at byte
  // row*1024 + ((c*16) ^ ((row&7)<<4))  [bank-conflict swizzle, G4]
  #pragma unroll
  for (int i = 0; i < 8; ++i) {
    const int g = t + i * 512;
    const int row = g >> 6, c = g & 63;
    const fv4* src = (const fv4*)(Wout + (size_t)(o0 + row) * H_ + c * 8);
    const sv8 v = pack8(src[0], src[1]);
    *(sv8*)((char*)Blds + row * 1024 + ((c * 16) ^ ((row & 7) << 4))) = v;
  }
  __syncthreads();

  const int w = t >> 6, l = t & 63;
  const int lr = l & 15, lg = l >> 4;
  const int nr = w * 32;   // wave handles 32 n-rows x 64 o-cols

  fv4 acc[2][4] = {};
  #pragma unroll
  for (int kk = 0; kk < 16; ++kk) {
    sv8 a[2];
    #pragma unroll
    for (int f = 0; f < 2; ++f)
      a[f] = *(const sv8*)(hbf + (size_t)(nr + f*16 + lr) * H_ + kk*32 + 8*lg);
    #pragma unroll
    for (int fo = 0; fo < 4; ++fo) {
      const int row = fo * 16 + lr;
      const sv8 b = *(const sv8*)((const char*)Blds + row * 1024 +
                                  ((kk*64 + lg*16) ^ ((row & 7) << 4)));
      #pragma unroll
      for (int f = 0; f < 2; ++f)
        acc[f][fo] = __builtin_amdgcn_mfma_f32_16x16x32_bf16(a[f], b, acc[f][fo], 0, 0, 0);
    }
  }
  #pragma unroll
  for (int fo = 0; fo < 4; ++fo) {
    const int oo = o0 + fo*16 + lr;
    const float bo = bout[oo];
    #pragma unroll
    for (int f = 0; f < 2; ++f) {
      #pragma unroll
      for (int r = 0; r < 4; ++r)
        pred[(size_t)(nr + f*16 + lg*4 + r) * O_ + oo] = acc[f][fo][r] + bo;
    }
  }
}

extern "C" void kernel_launch(void* const* d_in, const int* in_sizes, int n_in,
                              void* d_out, int out_size, void* d_ws, size_t ws_size,
                              hipStream_t stream) {
  const int*   x    = (const int*)  d_in[0];
  const float* eo   = (const float*)d_in[1];
  const float* hid  = (const float*)d_in[2];
  const float* cell = (const float*)d_in[3];
  const float* emb  = (const float*)d_in[4];
  const float* We   = (const float*)d_in[5];
  const float* be   = (const float*)d_in[6];
  const float* Wih  = (const float*)d_in[7];
  const float* Whh  = (const float*)d_in[8];
  const float* bih  = (const float*)d_in[9];
  const float* bhh  = (const float*)d_in[10];
  const float* Wout = (const float*)d_in[11];
  const float* bout = (const float*)d_in[12];

  float* pred = (float*)d_out;
  float* hout = pred + (size_t)N_ * O_;
  float* cout = hout + (size_t)N_ * H_;

  unsigned short* z    = (unsigned short*)d_ws;           // 917504 B
  unsigned short* hbf  = z + (size_t)N_ * KZ;             // 262144 B
  float* part = (float*)(hbf + (size_t)N_ * H_);          // 8 MB
  unsigned short* Wgbf = (unsigned short*)(part + (size_t)KSPLIT * N_ * GJ);  // 7.34 MB

  k_attn <<<dim3(256, 2), 1024, 0, stream>>>(x, eo, hid, emb, We, be,
                                             Wih, Whh, Wgbf, z);
  k_gates<<<dim3(32, 4, KSPLIT), 256, 0, stream>>>(z, Wgbf, part);
  k_lstm <<<512, 256, 0, stream>>>(part, cell, bih, bhh, hout, cout, hbf);
  k_pred <<<500, 512, 0, stream>>>(hbf, Wout, bout, pred);
}